// Round 1
// baseline (390.928 us; speedup 1.0000x reference)
//
#include <hip/hip_runtime.h>
#include <hip/hip_fp16.h>

// MHA forward, fp16 MFMA pipeline.
// B=2, N=4096, E=768, H=8, D=96.  SCALE applied AFTER softmax (faithful to ref).

typedef _Float16 half8 __attribute__((ext_vector_type(8)));
typedef _Float16 half4 __attribute__((ext_vector_type(4)));
typedef float   float4_ __attribute__((ext_vector_type(4)));

#define EMB   768
#define NSEQ  4096
#define MTOT  8192   // 2*4096
#define SCALE 0.102062072615966f  // 96^-0.5

__device__ __forceinline__ float4_ mfma16(half8 a, half8 b, float4_ c) {
    return __builtin_amdgcn_mfma_f32_16x16x32_f16(a, b, c, 0, 0, 0);
}

// ---------------- prep kernels ----------------

__global__ void cast_x(const float* __restrict__ x, _Float16* __restrict__ xb) {
    int i = blockIdx.x * 256 + threadIdx.x;           // 6144*256 = 1572864 = MTOT*EMB/4
    float4_ v = ((const float4_*)x)[i];
    half4 h = { (_Float16)v[0], (_Float16)v[1], (_Float16)v[2], (_Float16)v[3] };
    ((half4*)xb)[i] = h;
}

// wqkv[r][k] = W_{q|k|v}[k][r%768]  (r in 0..2303), wot[c][k] = Wo[k][c]
__global__ void prep_w(const float* __restrict__ Wq, const float* __restrict__ Wk,
                       const float* __restrict__ Wv, const float* __restrict__ Wo,
                       _Float16* __restrict__ wqkv, _Float16* __restrict__ wot) {
    int k = blockIdx.x * 256 + threadIdx.x;  // 0..767
    int r = blockIdx.y;                      // 0..3071
    if (r < 2304) {
        const float* W = (r < 768) ? Wq : (r < 1536) ? Wk : Wv;
        int c = r % 768;
        wqkv[(size_t)r * 768 + k] = (_Float16)W[(size_t)k * 768 + c];
    } else {
        int c = r - 2304;
        wot[(size_t)c * 768 + k] = (_Float16)Wo[(size_t)k * 768 + c];
    }
}

__global__ void prep_bias(const float* __restrict__ bq, const float* __restrict__ bk,
                          const float* __restrict__ bv, float* __restrict__ bqkv) {
    int i = blockIdx.x * 256 + threadIdx.x;  // 0..2303
    float v = (i < 768) ? bq[i] : (i < 1536) ? bk[i - 768] : bv[i - 1536];
    bqkv[i] = v;
}

// ---------------- GEMM: C = A(8192xK=768) @ Bt^T + bias ----------------
// A row-major [8192][768] f16, Bt row-major [N][768] f16 (i.e. B transposed).
// mode 0: N=2304, scatter epilogue -> Q[b][h][n][96], K[b][h][n][96], Vt[b][h][96][n] (f16)
// mode 1: N=768, out[gm][gc] = val (f32)
__global__ __launch_bounds__(256, 2) void gemm_kernel(
    const _Float16* __restrict__ A, const _Float16* __restrict__ Bt,
    const float* __restrict__ bias, int mode,
    _Float16* __restrict__ Qo, _Float16* __restrict__ Ko, _Float16* __restrict__ Vto,
    float* __restrict__ out)
{
    __shared__ alignas(16) _Float16 Al[128 * 72];   // 64 cols + 8 pad
    __shared__ alignas(16) _Float16 Bl[64 * 72];
    const int tid = threadIdx.x;
    const int lane = tid & 63, w = tid >> 6;
    const int wm = w >> 1, wn = w & 1;
    const int l15 = lane & 15, l4 = lane >> 4;
    const int m0 = blockIdx.y * 128;
    const int n0 = blockIdx.x * 64;

    float4_ acc[4][2] = {};

    for (int k0 = 0; k0 < 768; k0 += 64) {
        #pragma unroll
        for (int it = 0; it < 4; ++it) {                   // A tile: 128x64
            int idx = it * 256 + tid;
            int row = idx >> 3, c8 = idx & 7;
            *(half8*)(Al + row * 72 + c8 * 8) =
                *(const half8*)(A + (size_t)(m0 + row) * 768 + k0 + c8 * 8);
        }
        #pragma unroll
        for (int it = 0; it < 2; ++it) {                   // B tile: 64x64
            int idx = it * 256 + tid;
            int row = idx >> 3, c8 = idx & 7;
            *(half8*)(Bl + row * 72 + c8 * 8) =
                *(const half8*)(Bt + (size_t)(n0 + row) * 768 + k0 + c8 * 8);
        }
        __syncthreads();
        #pragma unroll
        for (int kc = 0; kc < 2; ++kc) {
            half8 bfr[2];
            #pragma unroll
            for (int nt = 0; nt < 2; ++nt)
                bfr[nt] = *(const half8*)(Bl + (wn * 32 + nt * 16 + l15) * 72 + kc * 32 + 8 * l4);
            #pragma unroll
            for (int mt = 0; mt < 4; ++mt) {
                half8 afr = *(const half8*)(Al + (wm * 64 + mt * 16 + l15) * 72 + kc * 32 + 8 * l4);
                #pragma unroll
                for (int nt = 0; nt < 2; ++nt)
                    acc[mt][nt] = mfma16(afr, bfr[nt], acc[mt][nt]);
            }
        }
        __syncthreads();
    }

    #pragma unroll
    for (int mt = 0; mt < 4; ++mt)
    #pragma unroll
    for (int nt = 0; nt < 2; ++nt) {
        int gc = n0 + wn * 32 + nt * 16 + l15;
        float bv_ = bias[gc];
        #pragma unroll
        for (int r = 0; r < 4; ++r) {
            int gm = m0 + wm * 64 + mt * 16 + l4 * 4 + r;
            float val = acc[mt][nt][r] + bv_;
            if (mode == 1) {
                out[(size_t)gm * 768 + gc] = val;
            } else {
                int b = gm >> 12, n = gm & 4095;
                _Float16 hv = (_Float16)val;
                if (gc < 768) {
                    int h = gc / 96, d = gc % 96;
                    Qo[(((size_t)(b * 8 + h)) * 4096 + n) * 96 + d] = hv;
                } else if (gc < 1536) {
                    int c = gc - 768, h = c / 96, d = c % 96;
                    Ko[(((size_t)(b * 8 + h)) * 4096 + n) * 96 + d] = hv;
                } else {
                    int c = gc - 1536, h = c / 96, d = c % 96;
                    Vto[(((size_t)(b * 8 + h)) * 96 + d) * 4096 + n] = hv;
                }
            }
        }
    }
}

// ---------------- flash attention ----------------
// grid (32 qblocks, 16 bh), 256 threads (4 waves x 32 q-rows). KV tile = 64.
__global__ __launch_bounds__(256, 2) void attn_kernel(
    const _Float16* __restrict__ Q, const _Float16* __restrict__ K,
    const _Float16* __restrict__ Vt, _Float16* __restrict__ AO)
{
    __shared__ alignas(16) _Float16 Kl[64 * 104];   // 96 + 8 pad
    __shared__ alignas(16) _Float16 Vtl[96 * 72];   // 64 + 8 pad
    __shared__ alignas(16) _Float16 Pl[4][32 * 72]; // per-wave P, 64 + 8 pad

    const int tid = threadIdx.x;
    const int lane = tid & 63, w = tid >> 6;
    const int l15 = lane & 15, l4 = lane >> 4;
    const int bh = blockIdx.y, qb = blockIdx.x;
    const size_t qkBase = (size_t)bh * 4096 * 96;
    const size_t vtBase = (size_t)bh * 96 * 4096;
    const int q0 = qb * 128 + w * 32;

    half8 qf[2][3];
    #pragma unroll
    for (int qt = 0; qt < 2; ++qt)
        #pragma unroll
        for (int kc = 0; kc < 3; ++kc)
            qf[qt][kc] = *(const half8*)(Q + qkBase + (size_t)(q0 + qt * 16 + l15) * 96 + kc * 32 + 8 * l4);

    float4_ o[2][6] = {};
    float m_run[2][4], l_run[2][4];
    #pragma unroll
    for (int qt = 0; qt < 2; ++qt)
        #pragma unroll
        for (int r = 0; r < 4; ++r) { m_run[qt][r] = -1e30f; l_run[qt][r] = 0.f; }

    for (int kv0 = 0; kv0 < 4096; kv0 += 64) {
        #pragma unroll
        for (int i = 0; i < 3; ++i) {                 // K tile 64x96 (12 half8/row)
            int idx = i * 256 + tid;
            int row = idx / 12, c = idx % 12;
            *(half8*)(Kl + row * 104 + c * 8) =
                *(const half8*)(K + qkBase + (size_t)(kv0 + row) * 96 + c * 8);
        }
        #pragma unroll
        for (int i = 0; i < 3; ++i) {                 // Vt tile 96x64 (8 half8/row)
            int idx = i * 256 + tid;
            int row = idx >> 3, c = idx & 7;
            *(half8*)(Vtl + row * 72 + c * 8) =
                *(const half8*)(Vt + vtBase + (size_t)row * 4096 + kv0 + c * 8);
        }
        __syncthreads();

        // S = Q K^T  (no pre-softmax scale, faithful to ref)
        float4_ s[2][4];
        #pragma unroll
        for (int qt = 0; qt < 2; ++qt)
        #pragma unroll
        for (int nt = 0; nt < 4; ++nt) {
            float4_ a = {};
            #pragma unroll
            for (int kc = 0; kc < 3; ++kc) {
                half8 bf = *(const half8*)(Kl + (nt * 16 + l15) * 104 + kc * 32 + 8 * l4);
                a = mfma16(qf[qt][kc], bf, a);
            }
            s[qt][nt] = a;
        }

        // online softmax (per 16-lane group; rows = 4*l4 + r)
        #pragma unroll
        for (int qt = 0; qt < 2; ++qt) {
            float pm[4];
            #pragma unroll
            for (int r = 0; r < 4; ++r)
                pm[r] = fmaxf(fmaxf(s[qt][0][r], s[qt][1][r]), fmaxf(s[qt][2][r], s[qt][3][r]));
            #pragma unroll
            for (int msk = 1; msk <= 8; msk <<= 1)
                #pragma unroll
                for (int r = 0; r < 4; ++r)
                    pm[r] = fmaxf(pm[r], __shfl_xor(pm[r], msk));
            float al[4], rs[4];
            #pragma unroll
            for (int r = 0; r < 4; ++r) {
                float mn = fmaxf(m_run[qt][r], pm[r]);
                al[r] = __expf(m_run[qt][r] - mn);
                m_run[qt][r] = mn;
                rs[r] = 0.f;
            }
            #pragma unroll
            for (int nt = 0; nt < 4; ++nt)
                #pragma unroll
                for (int r = 0; r < 4; ++r) {
                    float p = __expf(s[qt][nt][r] - m_run[qt][r]);
                    rs[r] += p;
                    Pl[w][(qt * 16 + l4 * 4 + r) * 72 + nt * 16 + l15] = (_Float16)p;
                }
            #pragma unroll
            for (int msk = 1; msk <= 8; msk <<= 1)
                #pragma unroll
                for (int r = 0; r < 4; ++r)
                    rs[r] += __shfl_xor(rs[r], msk);
            #pragma unroll
            for (int r = 0; r < 4; ++r)
                l_run[qt][r] = l_run[qt][r] * al[r] + rs[r];
            #pragma unroll
            for (int dt = 0; dt < 6; ++dt)
                #pragma unroll
                for (int r = 0; r < 4; ++r)
                    o[qt][dt][r] *= al[r];
        }
        __syncthreads();   // P visible (cross-lane), Vtl ready

        // O += P @ V
        #pragma unroll
        for (int kc = 0; kc < 2; ++kc) {
            half8 vb[6];
            #pragma unroll
            for (int dt = 0; dt < 6; ++dt)
                vb[dt] = *(const half8*)(Vtl + (dt * 16 + l15) * 72 + kc * 32 + 8 * l4);
            #pragma unroll
            for (int qt = 0; qt < 2; ++qt) {
                half8 pa = *(const half8*)(Pl[w] + (qt * 16 + l15) * 72 + kc * 32 + 8 * l4);
                #pragma unroll
                for (int dt = 0; dt < 6; ++dt)
                    o[qt][dt] = mfma16(pa, vb[dt], o[qt][dt]);
            }
        }
        __syncthreads();   // before next tile overwrites Kl/Vtl
    }

    const int b = bh >> 3, h = bh & 7;
    #pragma unroll
    for (int qt = 0; qt < 2; ++qt) {
        float inv[4];
        #pragma unroll
        for (int r = 0; r < 4; ++r) inv[r] = SCALE / l_run[qt][r];
        #pragma unroll
        for (int dt = 0; dt < 6; ++dt)
            #pragma unroll
            for (int r = 0; r < 4; ++r) {
                int n = q0 + qt * 16 + l4 * 4 + r;
                int col = h * 96 + dt * 16 + l15;
                AO[((size_t)(b * 4096 + n)) * 768 + col] = (_Float16)(o[qt][dt][r] * inv[r]);
            }
    }
}

// ---------------- launch ----------------

extern "C" void kernel_launch(void* const* d_in, const int* in_sizes, int n_in,
                              void* d_out, int out_size, void* d_ws, size_t ws_size,
                              hipStream_t stream) {
    const float* x  = (const float*)d_in[0];
    const float* Wq = (const float*)d_in[1];
    const float* bq = (const float*)d_in[2];
    const float* Wk = (const float*)d_in[3];
    const float* bk = (const float*)d_in[4];
    const float* Wv = (const float*)d_in[5];
    const float* bv = (const float*)d_in[6];
    const float* Wo = (const float*)d_in[7];
    const float* bo = (const float*)d_in[8];
    float* out = (float*)d_out;

    char* ws = (char*)d_ws;
    // layout (bytes):
    _Float16* xb   = (_Float16*)(ws);                 // 12,582,912  (also reused as AO)
    _Float16* wqkv = (_Float16*)(ws + 12582912);      //  3,538,944
    _Float16* wot  = (_Float16*)(ws + 16121856);      //  1,179,648
    float*    bqkv = (float*)   (ws + 17301504);      //      9,216
    _Float16* Qb   = (_Float16*)(ws + 17310720);      // 12,582,912
    _Float16* Kb   = (_Float16*)(ws + 29893632);      // 12,582,912
    _Float16* Vtb  = (_Float16*)(ws + 42476544);      // 12,582,912  -> total 55,059,456 B
    _Float16* AO   = xb;  // xb dead after QKV GEMM

    cast_x<<<6144, 256, 0, stream>>>(x, xb);
    prep_w<<<dim3(3, 3072), 256, 0, stream>>>(Wq, Wk, Wv, Wo, wqkv, wot);
    prep_bias<<<9, 256, 0, stream>>>(bq, bk, bv, bqkv);

    // QKV: M=8192, N=2304
    gemm_kernel<<<dim3(36, 64), 256, 0, stream>>>(xb, wqkv, bqkv, 0, Qb, Kb, Vtb, nullptr);

    attn_kernel<<<dim3(32, 16), 256, 0, stream>>>(Qb, Kb, Vtb, AO);

    // out-proj: M=8192, N=768, f32 out + bo
    gemm_kernel<<<dim3(12, 64), 256, 0, stream>>>(AO, wot, bo, 1, nullptr, nullptr, nullptr, out);
}

// Round 2
// 324.815 us; speedup vs baseline: 1.2035x; 1.2035x over previous
//
#include <hip/hip_runtime.h>
#include <hip/hip_fp16.h>

// MHA forward, fp16 MFMA pipeline.
// B=2, N=4096, E=768, H=8, D=96.  SCALE applied AFTER softmax (faithful to ref).
// Round 2: barrier-free attention; K/V stored fragment-linear, streamed from L2.

typedef _Float16 half8 __attribute__((ext_vector_type(8)));
typedef _Float16 half4 __attribute__((ext_vector_type(4)));
typedef float   float4_ __attribute__((ext_vector_type(4)));

#define EMB   768
#define NSEQ  4096
#define MTOT  8192   // 2*4096
#define SCALE 0.102062072615966f  // 96^-0.5

__device__ __forceinline__ float4_ mfma16(half8 a, half8 b, float4_ c) {
    return __builtin_amdgcn_mfma_f32_16x16x32_f16(a, b, c, 0, 0, 0);
}

// ---------------- prep kernels ----------------

__global__ void cast_x(const float* __restrict__ x, _Float16* __restrict__ xb) {
    int i = blockIdx.x * 256 + threadIdx.x;           // 6144*256 = 1572864 = MTOT*EMB/4
    float4_ v = ((const float4_*)x)[i];
    half4 h = { (_Float16)v[0], (_Float16)v[1], (_Float16)v[2], (_Float16)v[3] };
    ((half4*)xb)[i] = h;
}

// wqkv[r][k] = W_{q|k|v}[k][r%768]  (r in 0..2303), wot[c][k] = Wo[k][c]
__global__ void prep_w(const float* __restrict__ Wq, const float* __restrict__ Wk,
                       const float* __restrict__ Wv, const float* __restrict__ Wo,
                       _Float16* __restrict__ wqkv, _Float16* __restrict__ wot) {
    int k = blockIdx.x * 256 + threadIdx.x;  // 0..767
    int r = blockIdx.y;                      // 0..3071
    if (r < 2304) {
        const float* W = (r < 768) ? Wq : (r < 1536) ? Wk : Wv;
        int c = r % 768;
        wqkv[(size_t)r * 768 + k] = (_Float16)W[(size_t)k * 768 + c];
    } else {
        int c = r - 2304;
        wot[(size_t)c * 768 + k] = (_Float16)Wo[(size_t)k * 768 + c];
    }
}

__global__ void prep_bias(const float* __restrict__ bq, const float* __restrict__ bk,
                          const float* __restrict__ bv, float* __restrict__ bqkv) {
    int i = blockIdx.x * 256 + threadIdx.x;  // 0..2303
    float v = (i < 768) ? bq[i] : (i < 1536) ? bk[i - 768] : bv[i - 1536];
    bqkv[i] = v;
}

// ---------------- GEMM: C = A(8192xK=768) @ Bt^T + bias ----------------
// mode 0: N=2304, epilogue -> Q[bh][n][96] natural; K,V in MFMA-fragment-linear
//   Kf[bh][n/16][d/32][(d/8)&3][n&15][d&7]   (each frag = 512 halfs = 64 lanes x 16B)
//   Vf[bh][n/32][d/16][(n/8)&3][d&15][n&7]
// mode 1: N=768, out[gm][gc] = val (f32)
__global__ __launch_bounds__(256, 2) void gemm_kernel(
    const _Float16* __restrict__ A, const _Float16* __restrict__ Bt,
    const float* __restrict__ bias, int mode,
    _Float16* __restrict__ Qo, _Float16* __restrict__ Ko, _Float16* __restrict__ Vto,
    float* __restrict__ out)
{
    __shared__ alignas(16) _Float16 Al[128 * 72];   // 64 cols + 8 pad
    __shared__ alignas(16) _Float16 Bl[64 * 72];
    const int tid = threadIdx.x;
    const int lane = tid & 63, w = tid >> 6;
    const int wm = w >> 1, wn = w & 1;
    const int l15 = lane & 15, l4 = lane >> 4;
    const int m0 = blockIdx.y * 128;
    const int n0 = blockIdx.x * 64;

    float4_ acc[4][2] = {};

    for (int k0 = 0; k0 < 768; k0 += 64) {
        #pragma unroll
        for (int it = 0; it < 4; ++it) {                   // A tile: 128x64
            int idx = it * 256 + tid;
            int row = idx >> 3, c8 = idx & 7;
            *(half8*)(Al + row * 72 + c8 * 8) =
                *(const half8*)(A + (size_t)(m0 + row) * 768 + k0 + c8 * 8);
        }
        #pragma unroll
        for (int it = 0; it < 2; ++it) {                   // B tile: 64x64
            int idx = it * 256 + tid;
            int row = idx >> 3, c8 = idx & 7;
            *(half8*)(Bl + row * 72 + c8 * 8) =
                *(const half8*)(Bt + (size_t)(n0 + row) * 768 + k0 + c8 * 8);
        }
        __syncthreads();
        #pragma unroll
        for (int kc = 0; kc < 2; ++kc) {
            half8 bfr[2];
            #pragma unroll
            for (int nt = 0; nt < 2; ++nt)
                bfr[nt] = *(const half8*)(Bl + (wn * 32 + nt * 16 + l15) * 72 + kc * 32 + 8 * l4);
            #pragma unroll
            for (int mt = 0; mt < 4; ++mt) {
                half8 afr = *(const half8*)(Al + (wm * 64 + mt * 16 + l15) * 72 + kc * 32 + 8 * l4);
                #pragma unroll
                for (int nt = 0; nt < 2; ++nt)
                    acc[mt][nt] = mfma16(afr, bfr[nt], acc[mt][nt]);
            }
        }
        __syncthreads();
    }

    #pragma unroll
    for (int mt = 0; mt < 4; ++mt)
    #pragma unroll
    for (int nt = 0; nt < 2; ++nt) {
        int gc = n0 + wn * 32 + nt * 16 + l15;
        float bv_ = bias[gc];
        #pragma unroll
        for (int r = 0; r < 4; ++r) {
            int gm = m0 + wm * 64 + mt * 16 + l4 * 4 + r;
            float val = acc[mt][nt][r] + bv_;
            if (mode == 1) {
                out[(size_t)gm * 768 + gc] = val;
            } else {
                int b = gm >> 12, n = gm & 4095;
                _Float16 hv = (_Float16)val;
                if (gc < 768) {
                    int h = gc / 96, d = gc % 96;
                    Qo[(((size_t)(b * 8 + h)) * 4096 + n) * 96 + d] = hv;
                } else if (gc < 1536) {
                    int c = gc - 768, h = c / 96, d = c % 96;
                    int bh = b * 8 + h;
                    size_t idx = ((size_t)(bh * 256 + (n >> 4)) * 3 + (d >> 5)) * 512
                               + ((d >> 3) & 3) * 128 + (n & 15) * 8 + (d & 7);
                    Ko[idx] = hv;
                } else {
                    int c = gc - 1536, h = c / 96, d = c % 96;
                    int bh = b * 8 + h;
                    size_t idx = ((size_t)(bh * 128 + (n >> 5)) * 6 + (d >> 4)) * 512
                               + ((n >> 3) & 3) * 128 + (d & 15) * 8 + (n & 7);
                    Vto[idx] = hv;
                }
            }
        }
    }
}

// ---------------- flash attention (barrier-free, L2-streaming) ----------------
// 512 blocks x 256 thr (4 indep waves x 32 q-rows). KV tile = 64.
// Block->bh mapping keeps 2 bh per XCD so K/V (3MB) stays in the XCD's 4MB L2.
__global__ __launch_bounds__(256, 2) void attn_kernel(
    const _Float16* __restrict__ Q, const _Float16* __restrict__ Kf,
    const _Float16* __restrict__ Vf, _Float16* __restrict__ AO)
{
    __shared__ alignas(16) _Float16 Pl[4][32 * 72]; // per-wave P, 64 + 8 pad

    const int tid = threadIdx.x;
    const int lane = tid & 63, w = tid >> 6;
    const int l15 = lane & 15, l4 = lane >> 4;

    const int B = blockIdx.x;            // 0..511
    const int xcd = B & 7, j = B >> 3;   // assume XCD = linear_block_id % 8
    const int bh = 2 * xcd + (j >> 5);
    const int qb = j & 31;
    const int q0 = qb * 128 + w * 32;

    const size_t qBase = (size_t)bh * 4096 * 96;
    const _Float16* kfb = Kf + (size_t)bh * 256 * 1536;  // 256 kv16-tiles * 3 frags * 512
    const _Float16* vfb = Vf + (size_t)bh * 128 * 3072;  // 128 kv32-tiles * 6 frags * 512

    half8 qf[2][3];
    #pragma unroll
    for (int qt = 0; qt < 2; ++qt)
        #pragma unroll
        for (int kc = 0; kc < 3; ++kc)
            qf[qt][kc] = *(const half8*)(Q + qBase + (size_t)(q0 + qt * 16 + l15) * 96 + kc * 32 + 8 * l4);

    float4_ o[2][6] = {};
    float m_run[2][4], l_run[2][4];
    #pragma unroll
    for (int qt = 0; qt < 2; ++qt)
        #pragma unroll
        for (int r = 0; r < 4; ++r) { m_run[qt][r] = -1e30f; l_run[qt][r] = 0.f; }

    half8 kf[12], vf[12];
    #pragma unroll
    for (int nt = 0; nt < 4; ++nt)
        #pragma unroll
        for (int kc = 0; kc < 3; ++kc)
            kf[nt * 3 + kc] = *(const half8*)(kfb + ((size_t)(nt) * 3 + kc) * 512 + lane * 8);
    #pragma unroll
    for (int kc = 0; kc < 2; ++kc)
        #pragma unroll
        for (int dt = 0; dt < 6; ++dt)
            vf[kc * 6 + dt] = *(const half8*)(vfb + ((size_t)(kc) * 6 + dt) * 512 + lane * 8);

    for (int t = 0; t < 64; ++t) {
        // ---- S = Q K^T ----
        float4_ s[2][4];
        __builtin_amdgcn_s_setprio(1);
        #pragma unroll
        for (int qt = 0; qt < 2; ++qt)
            #pragma unroll
            for (int nt = 0; nt < 4; ++nt) {
                float4_ a = {};
                #pragma unroll
                for (int kc = 0; kc < 3; ++kc)
                    a = mfma16(qf[qt][kc], kf[nt * 3 + kc], a);
                s[qt][nt] = a;
            }
        __builtin_amdgcn_s_setprio(0);

        // ---- prefetch next K tile (kf regs dead after QK^T) ----
        const int tn = (t + 1) & 63;
        #pragma unroll
        for (int nt = 0; nt < 4; ++nt)
            #pragma unroll
            for (int kc = 0; kc < 3; ++kc)
                kf[nt * 3 + kc] = *(const half8*)(kfb + ((size_t)(tn * 4 + nt) * 3 + kc) * 512 + lane * 8);

        // ---- online softmax (rows = 4*l4+r, keys spread over l15 x nt) ----
        float pm[2][4];
        #pragma unroll
        for (int qt = 0; qt < 2; ++qt)
            #pragma unroll
            for (int r = 0; r < 4; ++r) {
                float v = fmaxf(fmaxf(s[qt][0][r], s[qt][1][r]), fmaxf(s[qt][2][r], s[qt][3][r]));
                #pragma unroll
                for (int msk = 1; msk <= 8; msk <<= 1)
                    v = fmaxf(v, __shfl_xor(v, msk));
                pm[qt][r] = v;
            }
        int ok = 1;
        #pragma unroll
        for (int qt = 0; qt < 2; ++qt)
            #pragma unroll
            for (int r = 0; r < 4; ++r)
                ok &= (pm[qt][r] <= m_run[qt][r] + 4.0f) ? 1 : 0;
        if (!__all(ok)) {    // rare: real rescale (defer-max, THR=4)
            #pragma unroll
            for (int qt = 0; qt < 2; ++qt)
                #pragma unroll
                for (int r = 0; r < 4; ++r) {
                    float mn = fmaxf(m_run[qt][r], pm[qt][r]);
                    float al = __expf(m_run[qt][r] - mn);
                    m_run[qt][r] = mn;
                    l_run[qt][r] *= al;
                    #pragma unroll
                    for (int dt = 0; dt < 6; ++dt)
                        o[qt][dt][r] *= al;
                }
        }
        float rs[2][4];
        #pragma unroll
        for (int qt = 0; qt < 2; ++qt) {
            #pragma unroll
            for (int r = 0; r < 4; ++r) rs[qt][r] = 0.f;
            #pragma unroll
            for (int nt = 0; nt < 4; ++nt)
                #pragma unroll
                for (int r = 0; r < 4; ++r) {
                    float p = __expf(s[qt][nt][r] - m_run[qt][r]);
                    rs[qt][r] += p;
                    Pl[w][(qt * 16 + l4 * 4 + r) * 72 + nt * 16 + l15] = (_Float16)p;
                }
        }
        #pragma unroll
        for (int qt = 0; qt < 2; ++qt)
            #pragma unroll
            for (int r = 0; r < 4; ++r) {
                float v = rs[qt][r];
                #pragma unroll
                for (int msk = 1; msk <= 8; msk <<= 1)
                    v += __shfl_xor(v, msk);
                l_run[qt][r] += v;
            }

        // ---- P visible to whole wave (same-wave LDS, no barrier needed) ----
        asm volatile("s_waitcnt lgkmcnt(0)" ::: "memory");
        half8 pa[2][2];
        #pragma unroll
        for (int qt = 0; qt < 2; ++qt)
            #pragma unroll
            for (int kc = 0; kc < 2; ++kc)
                pa[qt][kc] = *(const half8*)(Pl[w] + (qt * 16 + l15) * 72 + kc * 32 + 8 * l4);

        // ---- O += P @ V ----
        __builtin_amdgcn_s_setprio(1);
        #pragma unroll
        for (int qt = 0; qt < 2; ++qt)
            #pragma unroll
            for (int dt = 0; dt < 6; ++dt) {
                float4_ a = o[qt][dt];
                a = mfma16(pa[qt][0], vf[dt], a);
                a = mfma16(pa[qt][1], vf[6 + dt], a);
                o[qt][dt] = a;
            }
        __builtin_amdgcn_s_setprio(0);

        // ---- prefetch next V tile ----
        #pragma unroll
        for (int kc = 0; kc < 2; ++kc)
            #pragma unroll
            for (int dt = 0; dt < 6; ++dt)
                vf[kc * 6 + dt] = *(const half8*)(vfb + ((size_t)(tn * 2 + kc) * 6 + dt) * 512 + lane * 8);
    }

    const int b = bh >> 3, h = bh & 7;
    #pragma unroll
    for (int qt = 0; qt < 2; ++qt) {
        float inv[4];
        #pragma unroll
        for (int r = 0; r < 4; ++r) inv[r] = SCALE / l_run[qt][r];
        #pragma unroll
        for (int dt = 0; dt < 6; ++dt)
            #pragma unroll
            for (int r = 0; r < 4; ++r) {
                int n = q0 + qt * 16 + l4 * 4 + r;
                int col = h * 96 + dt * 16 + l15;
                AO[((size_t)(b * 4096 + n)) * 768 + col] = (_Float16)(o[qt][dt][r] * inv[r]);
            }
    }
}

// ---------------- launch ----------------

extern "C" void kernel_launch(void* const* d_in, const int* in_sizes, int n_in,
                              void* d_out, int out_size, void* d_ws, size_t ws_size,
                              hipStream_t stream) {
    const float* x  = (const float*)d_in[0];
    const float* Wq = (const float*)d_in[1];
    const float* bq = (const float*)d_in[2];
    const float* Wk = (const float*)d_in[3];
    const float* bk = (const float*)d_in[4];
    const float* Wv = (const float*)d_in[5];
    const float* bv = (const float*)d_in[6];
    const float* Wo = (const float*)d_in[7];
    const float* bo = (const float*)d_in[8];
    float* out = (float*)d_out;

    char* ws = (char*)d_ws;
    _Float16* xb   = (_Float16*)(ws);                 // 12,582,912  (reused as AO)
    _Float16* wqkv = (_Float16*)(ws + 12582912);      //  3,538,944
    _Float16* wot  = (_Float16*)(ws + 16121856);      //  1,179,648
    float*    bqkv = (float*)   (ws + 17301504);      //      9,216
    _Float16* Qb   = (_Float16*)(ws + 17310720);      // 12,582,912
    _Float16* Kfb  = (_Float16*)(ws + 29893632);      // 12,582,912
    _Float16* Vfb  = (_Float16*)(ws + 42476544);      // 12,582,912  -> total 55,059,456 B
    _Float16* AO   = xb;  // xb dead after QKV GEMM

    cast_x<<<6144, 256, 0, stream>>>(x, xb);
    prep_w<<<dim3(3, 3072), 256, 0, stream>>>(Wq, Wk, Wv, Wo, wqkv, wot);
    prep_bias<<<9, 256, 0, stream>>>(bq, bk, bv, bqkv);

    // QKV: M=8192, N=2304
    gemm_kernel<<<dim3(36, 64), 256, 0, stream>>>(xb, wqkv, bqkv, 0, Qb, Kfb, Vfb, nullptr);

    attn_kernel<<<512, 256, 0, stream>>>(Qb, Kfb, Vfb, AO);

    // out-proj: M=8192, N=768, f32 out + bo
    gemm_kernel<<<dim3(12, 64), 256, 0, stream>>>(AO, wot, bo, 1, nullptr, nullptr, nullptr, out);
}

// Round 3
// 281.501 us; speedup vs baseline: 1.3887x; 1.1539x over previous
//
#include <hip/hip_runtime.h>
#include <hip/hip_fp16.h>

// MHA forward, fp16 MFMA pipeline.
// B=2, N=4096, E=768, H=8, D=96.  SCALE applied AFTER softmax (faithful to ref).
// Round 3: swapped-QK^T 32x32 attention, in-register softmax, LDS-shared K/V.

typedef _Float16 half8 __attribute__((ext_vector_type(8)));
typedef _Float16 half4 __attribute__((ext_vector_type(4)));
typedef float   float4_ __attribute__((ext_vector_type(4)));
typedef float   f32x16 __attribute__((ext_vector_type(16)));

#define EMB   768
#define NSEQ  4096
#define MTOT  8192   // 2*4096
#define SCALE 0.102062072615966f  // 96^-0.5

__device__ __forceinline__ float4_ mfma16(half8 a, half8 b, float4_ c) {
    return __builtin_amdgcn_mfma_f32_16x16x32_f16(a, b, c, 0, 0, 0);
}
__device__ __forceinline__ f32x16 mfma32(half8 a, half8 b, f32x16 c) {
    return __builtin_amdgcn_mfma_f32_32x32x16_f16(a, b, c, 0, 0, 0);
}

// ---------------- prep kernels ----------------

__global__ void cast_x(const float* __restrict__ x, _Float16* __restrict__ xb) {
    int i = blockIdx.x * 256 + threadIdx.x;           // 6144*256 = 1572864 = MTOT*EMB/4
    float4_ v = ((const float4_*)x)[i];
    half4 h = { (_Float16)v[0], (_Float16)v[1], (_Float16)v[2], (_Float16)v[3] };
    ((half4*)xb)[i] = h;
}

// wqkv[r][k] = W_{q|k|v}[k][r%768]  (r in 0..2303), wot[c][k] = Wo[k][c]
__global__ void prep_w(const float* __restrict__ Wq, const float* __restrict__ Wk,
                       const float* __restrict__ Wv, const float* __restrict__ Wo,
                       _Float16* __restrict__ wqkv, _Float16* __restrict__ wot) {
    int k = blockIdx.x * 256 + threadIdx.x;  // 0..767
    int r = blockIdx.y;                      // 0..3071
    if (r < 2304) {
        const float* W = (r < 768) ? Wq : (r < 1536) ? Wk : Wv;
        int c = r % 768;
        wqkv[(size_t)r * 768 + k] = (_Float16)W[(size_t)k * 768 + c];
    } else {
        int c = r - 2304;
        wot[(size_t)c * 768 + k] = (_Float16)Wo[(size_t)k * 768 + c];
    }
}

__global__ void prep_bias(const float* __restrict__ bq, const float* __restrict__ bk,
                          const float* __restrict__ bv, float* __restrict__ bqkv) {
    int i = blockIdx.x * 256 + threadIdx.x;  // 0..2303
    float v = (i < 768) ? bq[i] : (i < 1536) ? bk[i - 768] : bv[i - 1536];
    bqkv[i] = v;
}

// ---------------- GEMM: C = A(8192xK=768) @ Bt^T + bias ----------------
// mode 0: N=2304, epilogue -> Q[bh][n][96] natural; K,V in 32x32-MFMA fragment-linear:
//   K A-frag (row k=n&31, contraction d): frag (t32=n>>5, dch=d>>4), lane=(d>>3&1)*32+(n&31), e=d&7
//   V B-frag (col d&31, contraction k):   frag (t64=n>>6, kk=(n>>4)&3, dt=d>>5), lane=((n>>3)&1)*32+(d&31), e=n&7
// mode 1: N=768, out[gm][gc] = val (f32)
__global__ __launch_bounds__(256, 2) void gemm_kernel(
    const _Float16* __restrict__ A, const _Float16* __restrict__ Bt,
    const float* __restrict__ bias, int mode,
    _Float16* __restrict__ Qo, _Float16* __restrict__ Ko, _Float16* __restrict__ Vto,
    float* __restrict__ out)
{
    __shared__ alignas(16) _Float16 Al[128 * 72];   // 64 cols + 8 pad
    __shared__ alignas(16) _Float16 Bl[64 * 72];
    const int tid = threadIdx.x;
    const int lane = tid & 63, w = tid >> 6;
    const int wm = w >> 1, wn = w & 1;
    const int l15 = lane & 15, l4 = lane >> 4;
    const int m0 = blockIdx.y * 128;
    const int n0 = blockIdx.x * 64;

    float4_ acc[4][2] = {};

    for (int k0 = 0; k0 < 768; k0 += 64) {
        #pragma unroll
        for (int it = 0; it < 4; ++it) {                   // A tile: 128x64
            int idx = it * 256 + tid;
            int row = idx >> 3, c8 = idx & 7;
            *(half8*)(Al + row * 72 + c8 * 8) =
                *(const half8*)(A + (size_t)(m0 + row) * 768 + k0 + c8 * 8);
        }
        #pragma unroll
        for (int it = 0; it < 2; ++it) {                   // B tile: 64x64
            int idx = it * 256 + tid;
            int row = idx >> 3, c8 = idx & 7;
            *(half8*)(Bl + row * 72 + c8 * 8) =
                *(const half8*)(Bt + (size_t)(n0 + row) * 768 + k0 + c8 * 8);
        }
        __syncthreads();
        #pragma unroll
        for (int kc = 0; kc < 2; ++kc) {
            half8 bfr[2];
            #pragma unroll
            for (int nt = 0; nt < 2; ++nt)
                bfr[nt] = *(const half8*)(Bl + (wn * 32 + nt * 16 + l15) * 72 + kc * 32 + 8 * l4);
            #pragma unroll
            for (int mt = 0; mt < 4; ++mt) {
                half8 afr = *(const half8*)(Al + (wm * 64 + mt * 16 + l15) * 72 + kc * 32 + 8 * l4);
                #pragma unroll
                for (int nt = 0; nt < 2; ++nt)
                    acc[mt][nt] = mfma16(afr, bfr[nt], acc[mt][nt]);
            }
        }
        __syncthreads();
    }

    #pragma unroll
    for (int mt = 0; mt < 4; ++mt)
    #pragma unroll
    for (int nt = 0; nt < 2; ++nt) {
        int gc = n0 + wn * 32 + nt * 16 + l15;
        float bv_ = bias[gc];
        #pragma unroll
        for (int r = 0; r < 4; ++r) {
            int gm = m0 + wm * 64 + mt * 16 + l4 * 4 + r;
            float val = acc[mt][nt][r] + bv_;
            if (mode == 1) {
                out[(size_t)gm * 768 + gc] = val;
            } else {
                int b = gm >> 12, n = gm & 4095;
                _Float16 hv = (_Float16)val;
                if (gc < 768) {
                    int h = gc / 96, d = gc % 96;
                    Qo[(((size_t)(b * 8 + h)) * 4096 + n) * 96 + d] = hv;
                } else if (gc < 1536) {
                    int c = gc - 768, h = c / 96, d = c % 96;
                    int bh = b * 8 + h;
                    size_t idx = (((size_t)bh * 128 + (n >> 5)) * 6 + (d >> 4)) * 512
                               + (size_t)((d >> 3) & 1) * 256 + (size_t)(n & 31) * 8 + (d & 7);
                    Ko[idx] = hv;
                } else {
                    int c = gc - 1536, h = c / 96, d = c % 96;
                    int bh = b * 8 + h;
                    size_t idx = (((size_t)bh * 64 + (n >> 6)) * 12 + ((n >> 4) & 3) * 3 + (d >> 5)) * 512
                               + (size_t)((n >> 3) & 1) * 256 + (size_t)(d & 31) * 8 + (n & 7);
                    Vto[idx] = hv;
                }
            }
        }
    }
}

// ---------------- flash attention (swapped QK^T, in-register softmax) ----------------
// 512 blocks x 256 thr (4 waves x 32 q-rows = 128 q/block). KV tile = 64.
// K/V staged once per block into LDS (fragment-linear, double-buffered, 2 barriers/tile).
// Lane owns q = lane&31 for softmax state; S^T rows (keys) spread over regs + lane>>5.
__global__ __launch_bounds__(256, 2) void attn_kernel(
    const _Float16* __restrict__ Q, const _Float16* __restrict__ Kf,
    const _Float16* __restrict__ Vf, _Float16* __restrict__ AO)
{
    __shared__ alignas(16) _Float16 lds[2][24 * 512];  // 2 x (12 K-frags + 12 V-frags)
    __shared__ float tab[4][32];

    const int tid = threadIdx.x;
    const int lane = tid & 63, w = tid >> 6;
    const int l31 = lane & 31, hi = lane >> 5;

    const int B = blockIdx.x;            // 0..511
    const int xcd = B & 7, j = B >> 3;   // XCD = linear_block_id % 8
    const int bh = 2 * xcd + (j >> 5);
    const int qb = j & 31;
    const int q0 = qb * 128 + w * 32;

    const size_t qBase = (size_t)bh * 4096 * 96;
    const _Float16* kfb = Kf + (size_t)bh * 393216;
    const _Float16* vfb = Vf + (size_t)bh * 393216;

    // Q as B-operand fragments: col=q=lane&31, contraction d = dch*16 + hi*8 + e
    half8 qf[6];
    #pragma unroll
    for (int dch = 0; dch < 6; ++dch)
        qf[dch] = *(const half8*)(Q + qBase + (size_t)(q0 + l31) * 96 + dch * 16 + hi * 8);

    f32x16 o0 = {}, o1 = {}, o2 = {};     // O[q-rows x 32d] for dt=0,1,2
    float m_run = -1e30f, l_run = 0.f;    // per-lane: q = lane&31

    const int fbase = w * 6;              // this wave stages frags fbase..fbase+5 (of 24)
    half8 streg[6];

    // prologue: stage tile 0 into buf 0
    #pragma unroll
    for (int i = 0; i < 6; ++i) {
        int f = fbase + i;
        const _Float16* g = (f < 12 ? kfb + (size_t)f * 512
                                    : vfb + (size_t)(f - 12) * 512) + lane * 8;
        streg[i] = *(const half8*)g;
    }
    #pragma unroll
    for (int i = 0; i < 6; ++i)
        *(half8*)(&lds[0][(fbase + i) * 512 + lane * 8]) = streg[i];
    __syncthreads();

    int cur = 0;
    for (int t = 0; t < 64; ++t) {
        const int tn = (t + 1) & 63;
        // ---- issue next-tile global loads (consumed after compute; T14) ----
        #pragma unroll
        for (int i = 0; i < 6; ++i) {
            int f = fbase + i;
            const _Float16* g = (f < 12 ? kfb + ((size_t)tn * 12 + f) * 512
                                        : vfb + ((size_t)tn * 12 + (f - 12)) * 512) + lane * 8;
            streg[i] = *(const half8*)g;
        }

        const _Float16* kb = &lds[cur][0];
        const _Float16* vb = &lds[cur][12 * 512];

        // ---- S^T = K Q^T : rows=keys, cols=q ----
        f32x16 s0 = {}, s1 = {};
        __builtin_amdgcn_s_setprio(1);
        #pragma unroll
        for (int dch = 0; dch < 6; ++dch) {
            half8 k0 = *(const half8*)(kb + (0 * 6 + dch) * 512 + lane * 8);
            half8 k1 = *(const half8*)(kb + (1 * 6 + dch) * 512 + lane * 8);
            s0 = mfma32(k0, qf[dch], s0);
            s1 = mfma32(k1, qf[dch], s1);
        }
        __builtin_amdgcn_s_setprio(0);

        // ---- in-register online softmax (lane owns q = lane&31) ----
        float lm = s0[0];
        #pragma unroll
        for (int r = 1; r < 16; ++r) lm = fmaxf(lm, s0[r]);
        #pragma unroll
        for (int r = 0; r < 16; ++r) lm = fmaxf(lm, s1[r]);
        float pmax = fmaxf(lm, __shfl_xor(lm, 32));
        if (__any(pmax > m_run + 4.0f)) {         // defer-max (T13, THR=4)
            float mnew = fmaxf(m_run, pmax);
            float al = __expf(m_run - mnew);
            m_run = mnew;
            l_run *= al;
            if (hi == 0) tab[w][l31] = al;
            asm volatile("s_waitcnt lgkmcnt(0)" ::: "memory");
            #pragma unroll
            for (int r = 0; r < 16; ++r) {
                float alr = tab[w][(r & 3) + 8 * (r >> 2) + 4 * hi];
                o0[r] *= alr; o1[r] *= alr; o2[r] *= alr;
            }
        }
        float ls = 0.f;
        uint32_t Lp0[8], Lp1[8];    // packed f16 pairs, [j*2 + c]
        #pragma unroll
        for (int jg = 0; jg < 4; ++jg) {
            float p0 = __expf(s0[4 * jg + 0] - m_run);
            float p1 = __expf(s0[4 * jg + 1] - m_run);
            float p2 = __expf(s0[4 * jg + 2] - m_run);
            float p3 = __expf(s0[4 * jg + 3] - m_run);
            ls += (p0 + p1) + (p2 + p3);
            union { _Float16 h[2]; uint32_t u; } a, b2;
            a.h[0] = (_Float16)p0; a.h[1] = (_Float16)p1;
            b2.h[0] = (_Float16)p2; b2.h[1] = (_Float16)p3;
            Lp0[jg * 2] = a.u; Lp0[jg * 2 + 1] = b2.u;
        }
        #pragma unroll
        for (int jg = 0; jg < 4; ++jg) {
            float p0 = __expf(s1[4 * jg + 0] - m_run);
            float p1 = __expf(s1[4 * jg + 1] - m_run);
            float p2 = __expf(s1[4 * jg + 2] - m_run);
            float p3 = __expf(s1[4 * jg + 3] - m_run);
            ls += (p0 + p1) + (p2 + p3);
            union { _Float16 h[2]; uint32_t u; } a, b2;
            a.h[0] = (_Float16)p0; a.h[1] = (_Float16)p1;
            b2.h[0] = (_Float16)p2; b2.h[1] = (_Float16)p3;
            Lp1[jg * 2] = a.u; Lp1[jg * 2 + 1] = b2.u;
        }
        l_run += ls + __shfl_xor(ls, 32);

        // ---- build PV A-fragments: pa[kt*2+kc], row=q, k = kc*16 + hi*8 + e ----
        half8 pa[4];
        #pragma unroll
        for (int kc = 0; kc < 2; ++kc) {
            uint32_t a0 = Lp0[4 * kc], a1 = Lp0[4 * kc + 1];
            uint32_t a2 = Lp0[4 * kc + 2], a3 = Lp0[4 * kc + 3];
            uint32_t w0 = __shfl_xor((int)a0, 32), w1 = __shfl_xor((int)a1, 32);
            uint32_t w2 = __shfl_xor((int)a2, 32), w3 = __shfl_xor((int)a3, 32);
            union { half8 h; uint32_t u[4]; } fr;
            fr.u[0] = hi ? w2 : a0;  fr.u[1] = hi ? w3 : a1;
            fr.u[2] = hi ? a2 : w0;  fr.u[3] = hi ? a3 : w1;
            pa[kc] = fr.h;
        }
        #pragma unroll
        for (int kc = 0; kc < 2; ++kc) {
            uint32_t a0 = Lp1[4 * kc], a1 = Lp1[4 * kc + 1];
            uint32_t a2 = Lp1[4 * kc + 2], a3 = Lp1[4 * kc + 3];
            uint32_t w0 = __shfl_xor((int)a0, 32), w1 = __shfl_xor((int)a1, 32);
            uint32_t w2 = __shfl_xor((int)a2, 32), w3 = __shfl_xor((int)a3, 32);
            union { half8 h; uint32_t u[4]; } fr;
            fr.u[0] = hi ? w2 : a0;  fr.u[1] = hi ? w3 : a1;
            fr.u[2] = hi ? a2 : w0;  fr.u[3] = hi ? a3 : w1;
            pa[2 + kc] = fr.h;
        }

        // ---- O += P @ V ----
        __builtin_amdgcn_s_setprio(1);
        #pragma unroll
        for (int kk = 0; kk < 4; ++kk) {
            half8 v0 = *(const half8*)(vb + (kk * 3 + 0) * 512 + lane * 8);
            half8 v1 = *(const half8*)(vb + (kk * 3 + 1) * 512 + lane * 8);
            half8 v2 = *(const half8*)(vb + (kk * 3 + 2) * 512 + lane * 8);
            o0 = mfma32(pa[kk], v0, o0);
            o1 = mfma32(pa[kk], v1, o1);
            o2 = mfma32(pa[kk], v2, o2);
        }
        __builtin_amdgcn_s_setprio(0);

        // ---- rotate double buffer ----
        __syncthreads();
        #pragma unroll
        for (int i = 0; i < 6; ++i)
            *(half8*)(&lds[cur ^ 1][(fbase + i) * 512 + lane * 8]) = streg[i];
        __syncthreads();
        cur ^= 1;
    }

    // ---- epilogue: O * SCALE/l, scatter to AO[b][n][h*96+d] ----
    if (hi == 0) tab[w][l31] = l_run;
    asm volatile("s_waitcnt lgkmcnt(0)" ::: "memory");
    const int b = bh >> 3, h = bh & 7;
    #pragma unroll
    for (int r = 0; r < 16; ++r) {
        int qrow = (r & 3) + 8 * (r >> 2) + 4 * hi;
        float inv = SCALE / tab[w][qrow];
        int n = q0 + qrow;
        size_t base = ((size_t)(b * 4096 + n)) * 768 + h * 96 + l31;
        AO[base]      = (_Float16)(o0[r] * inv);
        AO[base + 32] = (_Float16)(o1[r] * inv);
        AO[base + 64] = (_Float16)(o2[r] * inv);
    }
}

// ---------------- launch ----------------

extern "C" void kernel_launch(void* const* d_in, const int* in_sizes, int n_in,
                              void* d_out, int out_size, void* d_ws, size_t ws_size,
                              hipStream_t stream) {
    const float* x  = (const float*)d_in[0];
    const float* Wq = (const float*)d_in[1];
    const float* bq = (const float*)d_in[2];
    const float* Wk = (const float*)d_in[3];
    const float* bk = (const float*)d_in[4];
    const float* Wv = (const float*)d_in[5];
    const float* bv = (const float*)d_in[6];
    const float* Wo = (const float*)d_in[7];
    const float* bo = (const float*)d_in[8];
    float* out = (float*)d_out;

    char* ws = (char*)d_ws;
    _Float16* xb   = (_Float16*)(ws);                 // 12,582,912  (reused as AO)
    _Float16* wqkv = (_Float16*)(ws + 12582912);      //  3,538,944
    _Float16* wot  = (_Float16*)(ws + 16121856);      //  1,179,648
    float*    bqkv = (float*)   (ws + 17301504);      //      9,216
    _Float16* Qb   = (_Float16*)(ws + 17310720);      // 12,582,912
    _Float16* Kfb  = (_Float16*)(ws + 29893632);      // 12,582,912
    _Float16* Vfb  = (_Float16*)(ws + 42476544);      // 12,582,912  -> total 55,059,456 B
    _Float16* AO   = xb;  // xb dead after QKV GEMM

    cast_x<<<6144, 256, 0, stream>>>(x, xb);
    prep_w<<<dim3(3, 3072), 256, 0, stream>>>(Wq, Wk, Wv, Wo, wqkv, wot);
    prep_bias<<<9, 256, 0, stream>>>(bq, bk, bv, bqkv);

    // QKV: M=8192, N=2304
    gemm_kernel<<<dim3(36, 64), 256, 0, stream>>>(xb, wqkv, bqkv, 0, Qb, Kfb, Vfb, nullptr);

    attn_kernel<<<512, 256, 0, stream>>>(Qb, Kfb, Vfb, AO);

    // out-proj: M=8192, N=768, f32 out + bo
    gemm_kernel<<<dim3(12, 64), 256, 0, stream>>>(AO, wot, bo, 1, nullptr, nullptr, nullptr, out);
}